// Round 1
// baseline (390.366 us; speedup 1.0000x reference)
//
#include <hip/hip_runtime.h>

// GCN layer on MI355X.
// out = relu( (N·S) · W^T ),  N = D^-1/2 (A + 3I) D^-1/2   (reassociated)
//
// Pipeline:
//   1. k_init      : zero bucket cursors
//   2. k_partition : bin edges into buckets of 256 rows (LDS hist + chunk reservation)
//   3. k_build     : block per bucket: 256x48 slot table in LDS, degree, dis/cnt pack
//   4. k_prescale  : xb[slice][i][8dw] = bf16( dis[i] * seq[i] )  feature-SLICED layout
//   5. k_gather    : slice = bid&7 -> CP round-robin pins slice slab (3.2 MB) to one
//                    XCD's 4 MB L2. Old layout: every XCD pulled all 25.6 MB of xb
//                    through L2 (197 MB fetch, random-granule, miss path saturated at
//                    ~1.9 TB/s, implied latency ~2500 cyc). Sliced: gather becomes
//                    L2-hits; metadata re-read 8x but streaming.
//   6. k_gemm      : in-place on d_out via bf16 MFMA: out = relu(y @ W^T).

#define TPB 256
#define NBROWS 256          // rows per bucket
#define BCAP 4608           // edges per bucket capacity: mean 4096, +8 sigma
#define RCAP 48             // slots per row: Poisson(16), P(>48) ~ 5e-11 per row
#define EPB 2048            // edges per partition block (782 blocks ~ 3/CU; 8192 gave 0.77/CU)

typedef __attribute__((ext_vector_type(8))) short s16x8;   // 8 bf16 = 4 VGPR
typedef __attribute__((ext_vector_type(4))) float f32x4;   // MFMA C/D

__global__ void k_init(int* __restrict__ cursor, int m) {
    int i = blockIdx.x * TPB + threadIdx.x;
    if (i < m) cursor[i] = 0;
}

// ---------------- pass A: partition edges into row-buckets (256 thr) ----------------
__global__ __launch_bounds__(TPB) void k_partition(const int* __restrict__ ei,
                                                   const float* __restrict__ ew,
                                                   int* __restrict__ cursor,
                                                   int2* __restrict__ part,
                                                   int e, int nb) {
    __shared__ int hist[512];
    __shared__ int chunk[512];
    int t = threadIdx.x;
    hist[t] = 0; hist[t + 256] = 0;
    chunk[t] = 0; chunk[t + 256] = 0;
    __syncthreads();

    long base = (long)blockIdx.x * EPB;
    // phase 1: histogram only
    for (int j = 0; j < EPB / 256; ++j) {
        long idx = base + j * 256 + t;
        if (idx < e) atomicAdd(&hist[ei[idx] >> 8], 1);
    }
    __syncthreads();
    // reserve contiguous chunk per bucket (cursor padded to 64B)
    for (int b = t; b < nb; b += TPB) {
        int h = hist[b];
        chunk[b] = (h > 0) ? atomicAdd(&cursor[b * 16], h) : 0;
    }
    __syncthreads();
    hist[t] = 0; hist[t + 256] = 0;   // reuse as rank counters
    __syncthreads();
    // phase 2: re-read (L2-hot) and place
    for (int j = 0; j < EPB / 256; ++j) {
        long idx = base + j * 256 + t;
        if (idx < e) {
            int r = ei[idx];
            int c = ei[e + idx];
            float w = ew[idx];
            int b = r >> 8;
            int rank = atomicAdd(&hist[b], 1);
            int dst = chunk[b] + rank;
            if (dst < BCAP)
                part[(long)b * BCAP + dst] =
                    make_int2(((r & 255) << 17) | c, __float_as_int(w));
        }
    }
}

// ---------------- pass B: per-bucket slot table in LDS + degree ----------------
__global__ __launch_bounds__(TPB) void k_build(const int2* __restrict__ part,
                                               const int* __restrict__ cursor,
                                               unsigned* __restrict__ slotsG,
                                               float2* __restrict__ dc,
                                               float* __restrict__ dis, int n) {
    __shared__ unsigned lslot[NBROWS * RCAP];   // 48 KB
    __shared__ int rowcnt[NBROWS];
    int b = blockIdx.x, t = threadIdx.x;
    rowcnt[t] = 0;
    for (int j = t; j < NBROWS * RCAP; j += TPB) lslot[j] = 0;   // deterministic
    __syncthreads();

    int m = cursor[b * 16]; if (m > BCAP) m = BCAP;
    for (int i = t; i < m; i += TPB) {
        int2 en = part[(long)b * BCAP + i];
        int rl = ((unsigned)en.x) >> 17;        // row & 255
        int c  = en.x & 0x1FFFF;
        float w = __int_as_float(en.y);
        int pos = atomicAdd(&rowcnt[rl], 1);
        if (pos < RCAP) {
            int q = (int)(w * 32768.0f);
            if (q > 32767) q = 32767;
            lslot[rl * RCAP + pos] = ((unsigned)q << 17) | (unsigned)c;
        }
    }
    __syncthreads();

    int node = b * NBROWS + t;
    if (node < n) {
        int rc = rowcnt[t]; if (rc > RCAP) rc = RCAP;
        float s = 0.0f;
        for (int k = 0; k < rc; ++k)            // degree from quantized w (err ~2e-5 rel)
            s += ((float)(lslot[t * RCAP + k] >> 17) + 0.5f) * (1.0f / 32768.0f);
        float di = rsqrtf(3.0f + s);
        dis[node] = di;
        dc[node] = make_float2(di, __int_as_float(rc));   // one 8B load in gather
    }
    for (int j = t; j < NBROWS * RCAP; j += TPB)
        slotsG[(long)b * (NBROWS * RCAP) + j] = lslot[j];
}

// ---------------- prescale: xb[slice][node][8dw] = bf16(dis[i] * seq[i]) ----------------
__device__ inline unsigned bf16rne(float x) {
    unsigned u = __float_as_uint(x);
    u += 0x7FFF + ((u >> 16) & 1);
    return u >> 16;
}

__global__ __launch_bounds__(TPB) void k_prescale(const float* __restrict__ seq,
                                                  const float* __restrict__ dis,
                                                  unsigned* __restrict__ xb, int n) {
    long p = (long)blockIdx.x * TPB + threadIdx.x;   // pair index; wave spans one node
    if (p >= (long)n * 64) return;
    int node = (int)(p >> 6), fp = (int)(p & 63);    // feature pair 0..63
    float d = dis[node];
    float2 s = ((const float2*)seq)[p];
    // slice = fp>>3 owns feature pairs [slice*8, slice*8+8) = features [slice*16,+16)
    xb[((long)(fp >> 3) * n + node) * 8 + (fp & 7)] =
        bf16rne(d * s.x) | (bf16rne(d * s.y) << 16);
}

// ---------------- gather: slice-per-XCD, 8 lanes/edge, L2-resident slab ----------------
// slice = bid & 7  -> round-robin workgroup dispatch puts all blocks of a slice on one
// XCD; that slice's xb slab is n*32 B = 3.2 MB < 4 MB L2. 8-lane groups each process
// one edge (8 dwords = 16 bf16 features); wave handles 16 nodes sequentially.
__global__ __launch_bounds__(TPB) void k_gather(const unsigned* __restrict__ xb,
                                                const unsigned* __restrict__ slotsG,
                                                const float2* __restrict__ dc,
                                                float* __restrict__ y, int n) {
    int slice = blockIdx.x & 7;
    int chunk = blockIdx.x >> 3;
    int wave = threadIdx.x >> 6, lane = threadIdx.x & 63;
    int e8 = lane >> 3, d = lane & 7;                // (edge-in-batch, dword)
    const unsigned* xs = xb + (long)slice * n * 8;   // this slice's slab

    int node0 = chunk * 64 + wave * 16;
#pragma unroll 1
    for (int i = 0; i < 16; ++i) {
        int node = node0 + i;
        if (node >= n) break;
        float2 dcv = dc[node];
        float di = dcv.x;
        int m = __float_as_int(dcv.y);               // already clamped to RCAP

        unsigned s_l = (lane < m) ? slotsG[(long)node * RCAP + lane] : 0u;

        float2 acc = {0.0f, 0.0f};
        if (e8 == 0) {                               // self loop, group 0 only
            unsigned u = xs[(long)node * 8 + d];
            acc.x = 3.0f * __uint_as_float(u << 16);
            acc.y = 3.0f * __uint_as_float(u & 0xFFFF0000u);
        }

#pragma unroll 2
        for (int p = 0; p < m; p += 8) {
            int idx = p + e8;
            unsigned sl = __shfl(s_l, idx);          // packed (q<<17)|c
            int c = sl & 0x1FFFF;
            if (c > n - 1) c = n - 1;                // hard safety clamp
            float v = (idx < m)
                ? fmaf((float)(sl >> 17), 3.0517578125e-05f, 1.52587890625e-05f)
                : 0.0f;
            unsigned xv = xs[(long)c * 8 + d];       // 32B segment per 8-lane group
            acc.x = fmaf(v, __uint_as_float(xv << 16), acc.x);
            acc.y = fmaf(v, __uint_as_float(xv & 0xFFFF0000u), acc.y);
        }

        // reduce across the 8 edge-groups (lane bits 3,4,5)
        acc.x += __shfl_xor(acc.x, 8);
        acc.y += __shfl_xor(acc.y, 8);
        acc.x += __shfl_xor(acc.x, 16);
        acc.y += __shfl_xor(acc.y, 16);
        acc.x += __shfl_xor(acc.x, 32);
        acc.y += __shfl_xor(acc.y, 32);

        if (e8 == 0)                                 // lanes 0..7 store 64B
            ((float2*)(y + (long)node * 128 + slice * 16))[d] =
                make_float2(di * acc.x, di * acc.y);
    }
}

// ---------------- in-place MFMA GEMM: out[r] = relu(y[r] @ W^T) ----------------
// 128-row tile per block. y and W staged fp32->bf16 into LDS (32+32 KB).
// LDS layout: row-major bf16, 16 B granules XOR-swizzled: granule g of row r
// lives at shorts [r*128 + ((g ^ (r&15))<<3)].  Fragment reads (ds_read_b128)
// and staging writes both hit all 8 bank-groups evenly -> conflict-free.
// Fragments (verified layouts): A[m=lane&15][k=quad*8+i], B[k=quad*8+i][n=lane&15],
// C/D: col=lane&15, row=quad*4+reg.  Wave w owns rows [w*32, w*32+32).
// In-place safe: block fully reads its rows to LDS before any store.
__global__ __launch_bounds__(TPB) void k_gemm(float* __restrict__ y,
                                              const float* __restrict__ W, int n) {
    __shared__ short wlds[128 * 128];   // 32 KB bf16
    __shared__ short ylds[128 * 128];   // 32 KB bf16
    int t = threadIdx.x;
    long base = (long)blockIdx.x * 128;

#pragma unroll
    for (int i = 0; i < 8; ++i) {       // stage W: 2048 granules of 16 B
        int G = i * 256 + t;
        int j = G >> 4, g = G & 15;
        const float* src = W + j * 128 + g * 8;
        float4 f0 = *(const float4*)src;
        float4 f1 = *(const float4*)(src + 4);
        union { s16x8 s; uint4 u; } pk;
        pk.u.x = bf16rne(f0.x) | (bf16rne(f0.y) << 16);
        pk.u.y = bf16rne(f0.z) | (bf16rne(f0.w) << 16);
        pk.u.z = bf16rne(f1.x) | (bf16rne(f1.y) << 16);
        pk.u.w = bf16rne(f1.z) | (bf16rne(f1.w) << 16);
        *(s16x8*)&wlds[j * 128 + ((g ^ (j & 15)) << 3)] = pk.s;
    }
#pragma unroll
    for (int i = 0; i < 8; ++i) {       // stage y rows [base, base+128)
        int G = i * 256 + t;
        int r = G >> 4, g = G & 15;
        long gr = base + r; if (gr >= n) gr = n - 1;
        const float* src = y + gr * 128 + g * 8;
        float4 f0 = *(const float4*)src;
        float4 f1 = *(const float4*)(src + 4);
        union { s16x8 s; uint4 u; } pk;
        pk.u.x = bf16rne(f0.x) | (bf16rne(f0.y) << 16);
        pk.u.y = bf16rne(f0.z) | (bf16rne(f0.w) << 16);
        pk.u.z = bf16rne(f1.x) | (bf16rne(f1.y) << 16);
        pk.u.w = bf16rne(f1.z) | (bf16rne(f1.w) << 16);
        *(s16x8*)&ylds[r * 128 + ((g ^ (r & 15)) << 3)] = pk.s;
    }
    __syncthreads();

    int wave = t >> 6, lane = t & 63;
    int quad = lane >> 4, l15 = lane & 15;

    f32x4 acc[2][8];
#pragma unroll
    for (int h = 0; h < 2; ++h)
#pragma unroll
        for (int ct = 0; ct < 8; ++ct)
            acc[h][ct] = (f32x4){0.0f, 0.0f, 0.0f, 0.0f};

    int r0 = wave * 32 + l15;           // row-tile 2w   (m = l15)
    int r1 = wave * 32 + 16 + l15;      // row-tile 2w+1

#pragma unroll
    for (int kc = 0; kc < 4; ++kc) {
        int gA = kc * 4 + quad;         // k-granule for this lane's quad
        s16x8 a0 = *(const s16x8*)&ylds[r0 * 128 + ((gA ^ l15) << 3)];
        s16x8 a1 = *(const s16x8*)&ylds[r1 * 128 + ((gA ^ l15) << 3)];
#pragma unroll
        for (int ct = 0; ct < 8; ++ct) {
            int j = ct * 16 + l15;      // B col n = l15
            s16x8 b = *(const s16x8*)&wlds[j * 128 + ((gA ^ l15) << 3)];
            acc[0][ct] = __builtin_amdgcn_mfma_f32_16x16x32_bf16(a0, b, acc[0][ct], 0, 0, 0);
            acc[1][ct] = __builtin_amdgcn_mfma_f32_16x16x32_bf16(a1, b, acc[1][ct], 0, 0, 0);
        }
    }

    // C/D: local row = rt*16 + quad*4 + i, col = ct*16 + l15
#pragma unroll
    for (int h = 0; h < 2; ++h) {
        long rloc = wave * 32 + h * 16 + quad * 4;
#pragma unroll
        for (int i = 0; i < 4; ++i) {
            long gr = base + rloc + i;
            if (gr < n) {
                float* dst = y + gr * 128 + l15;
#pragma unroll
                for (int ct = 0; ct < 8; ++ct)
                    dst[ct * 16] = fmaxf(acc[h][ct][i], 0.0f);
            }
        }
    }
}

extern "C" void kernel_launch(void* const* d_in, const int* in_sizes, int n_in,
                              void* d_out, int out_size, void* d_ws, size_t ws_size,
                              hipStream_t stream) {
    const float* seq = (const float*)d_in[0];
    const float* ew  = (const float*)d_in[1];
    const float* W   = (const float*)d_in[2];
    const int*   ei  = (const int*)d_in[3];
    float* out = (float*)d_out;

    int n = in_sizes[0] / 128;   // 100000
    int e = in_sizes[1];         // 1600000
    int nb = (n + NBROWS - 1) / NBROWS;   // 391 buckets (<= 512 for partition LDS)

    // workspace layout (bytes): xb | part | slotsG | cursor | dc | dis  ~= 60.5 MB
    char* w8 = (char*)d_ws;
    unsigned* xb   = (unsigned*)w8;                                   // n*64 uints (sliced)
    size_t off = (size_t)n * 64 * 4;
    int2* part     = (int2*)(w8 + off);                               // nb*BCAP int2
    off += (size_t)nb * BCAP * 8;
    unsigned* slotsG = (unsigned*)(w8 + off);                         // nb*256*48 uints
    off += (size_t)nb * NBROWS * RCAP * 4;
    int* cursor    = (int*)(w8 + off);                                // nb*16 ints (64B pad)
    off += (size_t)nb * 16 * 4;
    float2* dc     = (float2*)(w8 + off);                             // n float2 (dis, cnt)
    off += (size_t)n * 8;
    float* dis     = (float*)(w8 + off);                              // n float

    k_init     <<<(nb * 16 + TPB - 1) / TPB, TPB, 0, stream>>>(cursor, nb * 16);
    k_partition<<<(e + EPB - 1) / EPB, TPB, 0, stream>>>(ei, ew, cursor, part, e, nb);
    k_build    <<<nb, TPB, 0, stream>>>(part, cursor, slotsG, dc, dis, n);
    k_prescale <<<(int)(((long)n * 64 + TPB - 1) / TPB), TPB, 0, stream>>>(seq, dis, xb, n);
    k_gather   <<<((n + 63) / 64) * 8, TPB, 0, stream>>>(xb, slotsG, dc, out, n);
    k_gemm     <<<(n + 127) / 128, TPB, 0, stream>>>(out, W, n);
}

// Round 2
// 278.775 us; speedup vs baseline: 1.4003x; 1.4003x over previous
//
#include <hip/hip_runtime.h>

// GCN layer on MI355X.
// out = relu( (N·S) · W^T ),  N = D^-1/2 (A + 3I) D^-1/2   (reassociated)
//
// Pipeline:
//   1. k_init      : zero bucket cursors
//   2. k_partition : bin edges into buckets of 256 rows (LDS hist + chunk reservation)
//   3. k_build     : block per bucket: 256x48 slot table in LDS, degree, dis/cnt pack
//   4. k_prescale  : xb[i] = bf16( dis[i] * seq[i] )   node-major, 25.6 MB
//   5. k_gather    : wave handles TWO nodes, edge loops interleaved -> 2x independent
//                    load streams. (R1 post-mortem: gather is latency-bound, nothing
//                    saturated: VALU 29%, HBM 31%, occ 72%. Slicing for L2 residency
//                    tripled VALU work and regressed 103->194 us; MLP is the lever.)
//   6. k_gemm      : in-place on d_out via bf16 MFMA: out = relu(y @ W^T).

#define TPB 256
#define NBROWS 256          // rows per bucket
#define BCAP 4608           // edges per bucket capacity: mean 4096, +8 sigma
#define RCAP 48             // slots per row: Poisson(16), P(>48) ~ 5e-11 per row
#define EPB 2048            // edges per partition block (782 blocks ~ 3/CU)

typedef __attribute__((ext_vector_type(8))) short s16x8;   // 8 bf16 = 4 VGPR
typedef __attribute__((ext_vector_type(4))) float f32x4;   // MFMA C/D

__global__ void k_init(int* __restrict__ cursor, int m) {
    int i = blockIdx.x * TPB + threadIdx.x;
    if (i < m) cursor[i] = 0;
}

// ---------------- pass A: partition edges into row-buckets (256 thr) ----------------
__global__ __launch_bounds__(TPB) void k_partition(const int* __restrict__ ei,
                                                   const float* __restrict__ ew,
                                                   int* __restrict__ cursor,
                                                   int2* __restrict__ part,
                                                   int e, int nb) {
    __shared__ int hist[512];
    __shared__ int chunk[512];
    int t = threadIdx.x;
    hist[t] = 0; hist[t + 256] = 0;
    chunk[t] = 0; chunk[t + 256] = 0;
    __syncthreads();

    long base = (long)blockIdx.x * EPB;
    // phase 1: histogram only
    for (int j = 0; j < EPB / 256; ++j) {
        long idx = base + j * 256 + t;
        if (idx < e) atomicAdd(&hist[ei[idx] >> 8], 1);
    }
    __syncthreads();
    // reserve contiguous chunk per bucket (cursor padded to 64B)
    for (int b = t; b < nb; b += TPB) {
        int h = hist[b];
        chunk[b] = (h > 0) ? atomicAdd(&cursor[b * 16], h) : 0;
    }
    __syncthreads();
    hist[t] = 0; hist[t + 256] = 0;   // reuse as rank counters
    __syncthreads();
    // phase 2: re-read (L2-hot) and place
    for (int j = 0; j < EPB / 256; ++j) {
        long idx = base + j * 256 + t;
        if (idx < e) {
            int r = ei[idx];
            int c = ei[e + idx];
            float w = ew[idx];
            int b = r >> 8;
            int rank = atomicAdd(&hist[b], 1);
            int dst = chunk[b] + rank;
            if (dst < BCAP)
                part[(long)b * BCAP + dst] =
                    make_int2(((r & 255) << 17) | c, __float_as_int(w));
        }
    }
}

// ---------------- pass B: per-bucket slot table in LDS + degree ----------------
__global__ __launch_bounds__(TPB) void k_build(const int2* __restrict__ part,
                                               const int* __restrict__ cursor,
                                               unsigned* __restrict__ slotsG,
                                               float2* __restrict__ dc,
                                               float* __restrict__ dis, int n) {
    __shared__ unsigned lslot[NBROWS * RCAP];   // 48 KB
    __shared__ int rowcnt[NBROWS];
    int b = blockIdx.x, t = threadIdx.x;
    rowcnt[t] = 0;
    for (int j = t; j < NBROWS * RCAP; j += TPB) lslot[j] = 0;   // deterministic
    __syncthreads();

    int m = cursor[b * 16]; if (m > BCAP) m = BCAP;
    for (int i = t; i < m; i += TPB) {
        int2 en = part[(long)b * BCAP + i];
        int rl = ((unsigned)en.x) >> 17;        // row & 255
        int c  = en.x & 0x1FFFF;
        float w = __int_as_float(en.y);
        int pos = atomicAdd(&rowcnt[rl], 1);
        if (pos < RCAP) {
            int q = (int)(w * 32768.0f);
            if (q > 32767) q = 32767;
            lslot[rl * RCAP + pos] = ((unsigned)q << 17) | (unsigned)c;
        }
    }
    __syncthreads();

    int node = b * NBROWS + t;
    if (node < n) {
        int rc = rowcnt[t]; if (rc > RCAP) rc = RCAP;
        float s = 0.0f;
        for (int k = 0; k < rc; ++k)            // degree from quantized w (err ~2e-5 rel)
            s += ((float)(lslot[t * RCAP + k] >> 17) + 0.5f) * (1.0f / 32768.0f);
        float di = rsqrtf(3.0f + s);
        dis[node] = di;
        dc[node] = make_float2(di, __int_as_float(rc));   // one 8B load in gather
    }
    for (int j = t; j < NBROWS * RCAP; j += TPB)
        slotsG[(long)b * (NBROWS * RCAP) + j] = lslot[j];
}

// ---------------- prescale: xb[i] = bf16(dis[i] * seq[i]), node-major ----------------
__device__ inline unsigned bf16rne(float x) {
    unsigned u = __float_as_uint(x);
    u += 0x7FFF + ((u >> 16) & 1);
    return u >> 16;
}

__global__ __launch_bounds__(TPB) void k_prescale(const float* __restrict__ seq,
                                                  const float* __restrict__ dis,
                                                  unsigned* __restrict__ xb, long npairs) {
    long p = (long)blockIdx.x * TPB + threadIdx.x;   // pair index; wave spans one row
    if (p >= npairs) return;
    float d = dis[p >> 6];
    float2 s = ((const float2*)seq)[p];
    xb[p] = bf16rne(d * s.x) | (bf16rne(d * s.y) << 16);
}

// ---------------- gather: 2 nodes per wave, interleaved edge loops ----------------
// Latency-bound kernel (R0: VALU 29%, HBM 31%, occ 72%). Two independent address
// streams per wave ~doubles outstanding 256B loads. Tails run single-stream so no
// wasted max-padding loads. mA/mB are wave-uniform -> tail branches don't diverge.
__global__ __launch_bounds__(TPB) void k_gather(const unsigned* __restrict__ xb,
                                                const unsigned* __restrict__ slotsG,
                                                const float2* __restrict__ dc,
                                                float* __restrict__ y, int n) {
    int wave = threadIdx.x >> 6, lane = threadIdx.x & 63;
    int nodeA = blockIdx.x * 8 + wave * 2;
    int nodeB = nodeA + 1;
    if (nodeA >= n) return;
    bool hasB = (nodeB < n);

    float2 dA = dc[nodeA];
    float2 dB = hasB ? dc[nodeB] : make_float2(0.0f, __int_as_float(0));
    int mA = __float_as_int(dA.y);
    int mB = __float_as_int(dB.y);

    unsigned sA = (lane < mA) ? slotsG[(long)nodeA * RCAP + lane] : 0u;
    unsigned sB = (lane < mB) ? slotsG[(long)nodeB * RCAP + lane] : 0u;
    int cAl = (int)(sA & 0x1FFFF); if (cAl > n - 1) cAl = n - 1;   // safety clamp
    int cBl = (int)(sB & 0x1FFFF); if (cBl > n - 1) cBl = n - 1;
    float vAl = (lane < mA) ? ((float)(sA >> 17) + 0.5f) * (1.0f / 32768.0f) : 0.0f;
    float vBl = (lane < mB) ? ((float)(sB >> 17) + 0.5f) * (1.0f / 32768.0f) : 0.0f;

    unsigned uA = xb[(long)nodeA * 64 + lane];
    unsigned uB = hasB ? xb[(long)nodeB * 64 + lane] : 0u;
    float2 accA, accB;
    accA.x = 3.0f * __uint_as_float(uA << 16);
    accA.y = 3.0f * __uint_as_float(uA & 0xFFFF0000u);
    accB.x = 3.0f * __uint_as_float(uB << 16);
    accB.y = 3.0f * __uint_as_float(uB & 0xFFFF0000u);

    int mlo = (mA < mB) ? mA : mB;
#pragma unroll 4
    for (int p = 0; p < mlo; ++p) {
        int   ca = __shfl(cAl, p);
        float va = __shfl(vAl, p);
        int   cb = __shfl(cBl, p);
        float vb = __shfl(vBl, p);
        unsigned xa = xb[(long)ca * 64 + lane];
        unsigned xv = xb[(long)cb * 64 + lane];
        accA.x = fmaf(va, __uint_as_float(xa << 16), accA.x);
        accA.y = fmaf(va, __uint_as_float(xa & 0xFFFF0000u), accA.y);
        accB.x = fmaf(vb, __uint_as_float(xv << 16), accB.x);
        accB.y = fmaf(vb, __uint_as_float(xv & 0xFFFF0000u), accB.y);
    }
    if (mA > mlo) {
#pragma unroll 4
        for (int p = mlo; p < mA; ++p) {
            int   ca = __shfl(cAl, p);
            float va = __shfl(vAl, p);
            unsigned xa = xb[(long)ca * 64 + lane];
            accA.x = fmaf(va, __uint_as_float(xa << 16), accA.x);
            accA.y = fmaf(va, __uint_as_float(xa & 0xFFFF0000u), accA.y);
        }
    } else if (mB > mlo) {
#pragma unroll 4
        for (int p = mlo; p < mB; ++p) {
            int   cb = __shfl(cBl, p);
            float vb = __shfl(vBl, p);
            unsigned xv = xb[(long)cb * 64 + lane];
            accB.x = fmaf(vb, __uint_as_float(xv << 16), accB.x);
            accB.y = fmaf(vb, __uint_as_float(xv & 0xFFFF0000u), accB.y);
        }
    }

    ((float2*)(y + (long)nodeA * 128))[lane] = make_float2(dA.x * accA.x, dA.x * accA.y);
    if (hasB)
        ((float2*)(y + (long)nodeB * 128))[lane] = make_float2(dB.x * accB.x, dB.x * accB.y);
}

// ---------------- in-place MFMA GEMM: out[r] = relu(y[r] @ W^T) ----------------
// 128-row tile per block. y and W staged fp32->bf16 into LDS (32+32 KB).
// LDS layout: row-major bf16, 16 B granules XOR-swizzled: granule g of row r
// lives at shorts [r*128 + ((g ^ (r&15))<<3)].  Fragment reads (ds_read_b128)
// and staging writes both hit all 8 bank-groups evenly -> conflict-free.
// Fragments (verified layouts): A[m=lane&15][k=quad*8+i], B[k=quad*8+i][n=lane&15],
// C/D: col=lane&15, row=quad*4+reg.  Wave w owns rows [w*32, w*32+32).
// In-place safe: block fully reads its rows to LDS before any store.
__global__ __launch_bounds__(TPB) void k_gemm(float* __restrict__ y,
                                              const float* __restrict__ W, int n) {
    __shared__ short wlds[128 * 128];   // 32 KB bf16
    __shared__ short ylds[128 * 128];   // 32 KB bf16
    int t = threadIdx.x;
    long base = (long)blockIdx.x * 128;

#pragma unroll
    for (int i = 0; i < 8; ++i) {       // stage W: 2048 granules of 16 B
        int G = i * 256 + t;
        int j = G >> 4, g = G & 15;
        const float* src = W + j * 128 + g * 8;
        float4 f0 = *(const float4*)src;
        float4 f1 = *(const float4*)(src + 4);
        union { s16x8 s; uint4 u; } pk;
        pk.u.x = bf16rne(f0.x) | (bf16rne(f0.y) << 16);
        pk.u.y = bf16rne(f0.z) | (bf16rne(f0.w) << 16);
        pk.u.z = bf16rne(f1.x) | (bf16rne(f1.y) << 16);
        pk.u.w = bf16rne(f1.z) | (bf16rne(f1.w) << 16);
        *(s16x8*)&wlds[j * 128 + ((g ^ (j & 15)) << 3)] = pk.s;
    }
#pragma unroll
    for (int i = 0; i < 8; ++i) {       // stage y rows [base, base+128)
        int G = i * 256 + t;
        int r = G >> 4, g = G & 15;
        long gr = base + r; if (gr >= n) gr = n - 1;
        const float* src = y + gr * 128 + g * 8;
        float4 f0 = *(const float4*)src;
        float4 f1 = *(const float4*)(src + 4);
        union { s16x8 s; uint4 u; } pk;
        pk.u.x = bf16rne(f0.x) | (bf16rne(f0.y) << 16);
        pk.u.y = bf16rne(f0.z) | (bf16rne(f0.w) << 16);
        pk.u.z = bf16rne(f1.x) | (bf16rne(f1.y) << 16);
        pk.u.w = bf16rne(f1.z) | (bf16rne(f1.w) << 16);
        *(s16x8*)&ylds[r * 128 + ((g ^ (r & 15)) << 3)] = pk.s;
    }
    __syncthreads();

    int wave = t >> 6, lane = t & 63;
    int quad = lane >> 4, l15 = lane & 15;

    f32x4 acc[2][8];
#pragma unroll
    for (int h = 0; h < 2; ++h)
#pragma unroll
        for (int ct = 0; ct < 8; ++ct)
            acc[h][ct] = (f32x4){0.0f, 0.0f, 0.0f, 0.0f};

    int r0 = wave * 32 + l15;           // row-tile 2w   (m = l15)
    int r1 = wave * 32 + 16 + l15;      // row-tile 2w+1

#pragma unroll
    for (int kc = 0; kc < 4; ++kc) {
        int gA = kc * 4 + quad;         // k-granule for this lane's quad
        s16x8 a0 = *(const s16x8*)&ylds[r0 * 128 + ((gA ^ l15) << 3)];
        s16x8 a1 = *(const s16x8*)&ylds[r1 * 128 + ((gA ^ l15) << 3)];
#pragma unroll
        for (int ct = 0; ct < 8; ++ct) {
            int j = ct * 16 + l15;      // B col n = l15
            s16x8 b = *(const s16x8*)&wlds[j * 128 + ((gA ^ l15) << 3)];
            acc[0][ct] = __builtin_amdgcn_mfma_f32_16x16x32_bf16(a0, b, acc[0][ct], 0, 0, 0);
            acc[1][ct] = __builtin_amdgcn_mfma_f32_16x16x32_bf16(a1, b, acc[1][ct], 0, 0, 0);
        }
    }

    // C/D: local row = rt*16 + quad*4 + i, col = ct*16 + l15
#pragma unroll
    for (int h = 0; h < 2; ++h) {
        long rloc = wave * 32 + h * 16 + quad * 4;
#pragma unroll
        for (int i = 0; i < 4; ++i) {
            long gr = base + rloc + i;
            if (gr < n) {
                float* dst = y + gr * 128 + l15;
#pragma unroll
                for (int ct = 0; ct < 8; ++ct)
                    dst[ct * 16] = fmaxf(acc[h][ct][i], 0.0f);
            }
        }
    }
}

extern "C" void kernel_launch(void* const* d_in, const int* in_sizes, int n_in,
                              void* d_out, int out_size, void* d_ws, size_t ws_size,
                              hipStream_t stream) {
    const float* seq = (const float*)d_in[0];
    const float* ew  = (const float*)d_in[1];
    const float* W   = (const float*)d_in[2];
    const int*   ei  = (const int*)d_in[3];
    float* out = (float*)d_out;

    int n = in_sizes[0] / 128;   // 100000
    int e = in_sizes[1];         // 1600000
    int nb = (n + NBROWS - 1) / NBROWS;   // 391 buckets (<= 512 for partition LDS)

    // workspace layout (bytes): xb | part | slotsG | cursor | dc | dis  ~= 60.5 MB
    char* w8 = (char*)d_ws;
    unsigned* xb   = (unsigned*)w8;                                   // n*64 uints
    size_t off = (size_t)n * 64 * 4;
    int2* part     = (int2*)(w8 + off);                               // nb*BCAP int2
    off += (size_t)nb * BCAP * 8;
    unsigned* slotsG = (unsigned*)(w8 + off);                         // nb*256*48 uints
    off += (size_t)nb * NBROWS * RCAP * 4;
    int* cursor    = (int*)(w8 + off);                                // nb*16 ints (64B pad)
    off += (size_t)nb * 16 * 4;
    float2* dc     = (float2*)(w8 + off);                             // n float2 (dis, cnt)
    off += (size_t)n * 8;
    float* dis     = (float*)(w8 + off);                              // n float

    long npairs = (long)n * 64;

    k_init     <<<(nb * 16 + TPB - 1) / TPB, TPB, 0, stream>>>(cursor, nb * 16);
    k_partition<<<(e + EPB - 1) / EPB, TPB, 0, stream>>>(ei, ew, cursor, part, e, nb);
    k_build    <<<nb, TPB, 0, stream>>>(part, cursor, slotsG, dc, dis, n);
    k_prescale <<<(int)((npairs + TPB - 1) / TPB), TPB, 0, stream>>>(seq, dis, xb, npairs);
    k_gather   <<<(n + 7) / 8, TPB, 0, stream>>>(xb, slotsG, dc, out, n);
    k_gemm     <<<(n + 127) / 128, TPB, 0, stream>>>(out, W, n);
}